// Round 3
// baseline (308.867 us; speedup 1.0000x reference)
//
#include <hip/hip_runtime.h>
#include <hip/hip_bf16.h>
#include <cstdint>

// Problem constants (reference: N=16384, F=1024, H=256)
#define NR 16384
#define NF 1024
#define NH 256

typedef __bf16 bf16x8 __attribute__((ext_vector_type(8)));
typedef float f32x4 __attribute__((ext_vector_type(4)));
typedef unsigned short us8 __attribute__((ext_vector_type(8)));

static __device__ __forceinline__ unsigned short f2bf(float f) {
    unsigned u = __float_as_uint(f);
    u += 0x7FFFu + ((u >> 16) & 1u);   // RNE
    return (unsigned short)(u >> 16);
}

// two floats -> packed bf16 pair (low word = first arg)
static __device__ __forceinline__ unsigned cvt2(float a, float b) {
    return ((unsigned)f2bf(b) << 16) | (unsigned)f2bf(a);
}

// async global->LDS, 16 B per lane. LDS dest is wave-uniform base + lane*16,
// so lp MUST be linear in lane with stride 16 (it is, everywhere below).
__device__ __forceinline__ void gl2lds16(const void* gp, void* lp) {
    __builtin_amdgcn_global_load_lds(
        (const __attribute__((address_space(1))) unsigned int*)gp,
        (__attribute__((address_space(3))) unsigned int*)lp, 16, 0, 0);
}

// ---------------------------------------------------------------------------
// prep: WeT[n][k] = bf16(We[k][n])  (256x1024), WdT[n][k] = bf16(Wd[k][n]) (1024x256)
// ---------------------------------------------------------------------------
__global__ __launch_bounds__(256) void prep_kernel(
    const float* __restrict__ We, const float* __restrict__ Wd,
    unsigned short* __restrict__ WeT, unsigned short* __restrict__ WdT) {
    int tid = blockIdx.x * 256 + threadIdx.x;
    if (tid < NH * NF) {
        int n = tid >> 10, k = tid & (NF - 1);
        WeT[tid] = f2bf(We[(size_t)k * NH + n]);
    } else {
        int t2 = tid - NH * NF;
        int n = t2 >> 8, k = t2 & (NH - 1);
        WdT[t2] = f2bf(Wd[(size_t)k * NF + n]);
    }
}

// ---------------------------------------------------------------------------
// GEMM1: g[16384][256](bf16) = X @ We + be ; also cpart[row] += (g row) . Wc
// tile 64(m) x 128(n), BK=32, 4 waves (each 32x64), global_load_lds staging.
// A staged as fp32 with 8-slot XOR swizzle; B bf16 with 4-slot XOR swizzle.
// mfma(B,A,acc) -> per lane: m = li (fixed), n = q*4+reg (consecutive 4).
// ---------------------------------------------------------------------------
__global__ __launch_bounds__(256) void gemm1_kernel(
    const float* __restrict__ X, const unsigned short* __restrict__ WeT,
    const float* __restrict__ be, const float* __restrict__ Wc,
    unsigned short* __restrict__ g, float* __restrict__ cpart) {
    __shared__ float As[64 * 32];            // 8 KB, row = 128 B = 8 slots of 16 B
    __shared__ unsigned short Bs[128 * 32];  // 8 KB, row = 64 B  = 4 slots of 16 B
    const int t = threadIdx.x;
    const int m0 = blockIdx.x * 64;
    const int n0 = blockIdx.y * 128;
    const int w = t >> 6, lane = t & 63;
    const int q = lane >> 4, li = lane & 15;
    const int wr = (w >> 1) * 32, wc = (w & 1) * 64;

    // staging address precompute (swizzled k-chunk per lane)
    const int arow = t >> 3;                      // + p*32
    const int ac = (t & 7) ^ ((t >> 3) & 7);      // fp32 chunk of 4
    const int brow = t >> 2;                      // + p*64
    const int bc = (t & 3) ^ ((t >> 3) & 3);      // bf16 chunk of 8
    const float* Xg0 = X + (size_t)(m0 + arow) * NF + ac * 4;
    const float* Xg1 = X + (size_t)(m0 + 32 + arow) * NF + ac * 4;
    const unsigned short* Bg0 = WeT + (size_t)(n0 + brow) * NF + bc * 8;
    const unsigned short* Bg1 = WeT + (size_t)(n0 + 64 + brow) * NF + bc * 8;
    float* Al = As + t * 4;              // byte t*16
    unsigned short* Bl = Bs + t * 8;     // byte t*16

    f32x4 acc[2][4] = {};
    for (int k0 = 0; k0 < NF; k0 += 32) {
        gl2lds16(Xg0 + k0, Al);
        gl2lds16(Xg1 + k0, Al + 1024);   // +4096 B
        gl2lds16(Bg0 + k0, Bl);
        gl2lds16(Bg1 + k0, Bl + 2048);   // +4096 B
        __syncthreads();

        bf16x8 af[2], bf[4];
#pragma unroll
        for (int i = 0; i < 2; i++) {
            int r = wr + i * 16 + li;
            int s0 = (2 * q) ^ (r & 7);
            int s1 = s0 ^ 1;
            f32x4 lo = *(const f32x4*)&As[r * 32 + s0 * 4];
            f32x4 hi = *(const f32x4*)&As[r * 32 + s1 * 4];
            uint4 pk;
            pk.x = cvt2(lo[0], lo[1]); pk.y = cvt2(lo[2], lo[3]);
            pk.z = cvt2(hi[0], hi[1]); pk.w = cvt2(hi[2], hi[3]);
            af[i] = __builtin_bit_cast(bf16x8, pk);
        }
#pragma unroll
        for (int j = 0; j < 4; j++) {
            int r = wc + j * 16 + li;
            int s = q ^ ((r >> 1) & 3);
            bf[j] = __builtin_bit_cast(bf16x8, *(const us8*)&Bs[r * 32 + s * 8]);
        }
#pragma unroll
        for (int i = 0; i < 2; i++)
#pragma unroll
            for (int j = 0; j < 4; j++)
                acc[i][j] = __builtin_amdgcn_mfma_f32_16x16x32_bf16(bf[j], af[i], acc[i][j], 0, 0, 0);
        __syncthreads();
    }

    // epilogue: ushort4 g stores + fused critic partial dot products
#pragma unroll
    for (int i = 0; i < 2; i++) {
        float csum = 0.f;
#pragma unroll
        for (int j = 0; j < 4; j++) {
            int colb = n0 + wc + j * 16 + q * 4;
            float4 be4 = *(const float4*)&be[colb];
            float4 wc4 = *(const float4*)&Wc[colb];
            float v0 = acc[i][j][0] + be4.x;
            float v1 = acc[i][j][1] + be4.y;
            float v2 = acc[i][j][2] + be4.z;
            float v3 = acc[i][j][3] + be4.w;
            csum += v0 * wc4.x + v1 * wc4.y + v2 * wc4.z + v3 * wc4.w;
            ushort4 st = { f2bf(v0), f2bf(v1), f2bf(v2), f2bf(v3) };
            *(ushort4*)&g[(size_t)(m0 + wr + i * 16 + li) * NH + colb] = st;
        }
        csum += __shfl_down(csum, 32);
        csum += __shfl_down(csum, 16);
        if (lane < 16) atomicAdd(&cpart[m0 + wr + i * 16 + lane], csum);
    }
}

// ---------------------------------------------------------------------------
// GEMM2 fused MSE: rec = g @ Wd + bd; sum((rec-X)^2); no rec materialization.
// tile 64 x 128, BK=32, K=256. Epilogue X reads are float4 (operand swap).
// A tile: 64 rows x 32 k bf16 = 4 KB = 256 lanes x 16 B (all threads stage).
// ---------------------------------------------------------------------------
__global__ __launch_bounds__(256) void gemm2_kernel(
    const unsigned short* __restrict__ g, const unsigned short* __restrict__ WdT,
    const float* __restrict__ bd, const float* __restrict__ X,
    float* __restrict__ mse_acc) {
    __shared__ unsigned short As[64 * 32];   // 4 KB
    __shared__ unsigned short Bs[128 * 32];  // 8 KB
    const int t = threadIdx.x;
    const int m0 = blockIdx.x * 64;
    const int n0 = blockIdx.y * 128;
    const int w = t >> 6, lane = t & 63;
    const int q = lane >> 4, li = lane & 15;
    const int wr = (w >> 1) * 32, wc = (w & 1) * 64;

    const int crow = t >> 2;
    const int cc = (t & 3) ^ ((t >> 3) & 3);
    const unsigned short* Ag  = g   + (size_t)(m0 + crow) * NH + cc * 8;
    const unsigned short* Bg0 = WdT + (size_t)(n0 + crow) * NH + cc * 8;
    const unsigned short* Bg1 = WdT + (size_t)(n0 + 64 + crow) * NH + cc * 8;
    unsigned short* Al = As + t * 8;
    unsigned short* Bl = Bs + t * 8;

    f32x4 acc[2][4] = {};
    for (int k0 = 0; k0 < NH; k0 += 32) {
        gl2lds16(Ag + k0, Al);
        gl2lds16(Bg0 + k0, Bl);
        gl2lds16(Bg1 + k0, Bl + 2048);
        __syncthreads();

        bf16x8 af[2], bf[4];
#pragma unroll
        for (int i = 0; i < 2; i++) {
            int r = wr + i * 16 + li;
            int s = q ^ ((r >> 1) & 3);
            af[i] = __builtin_bit_cast(bf16x8, *(const us8*)&As[r * 32 + s * 8]);
        }
#pragma unroll
        for (int j = 0; j < 4; j++) {
            int r = wc + j * 16 + li;
            int s = q ^ ((r >> 1) & 3);
            bf[j] = __builtin_bit_cast(bf16x8, *(const us8*)&Bs[r * 32 + s * 8]);
        }
#pragma unroll
        for (int i = 0; i < 2; i++)
#pragma unroll
            for (int j = 0; j < 4; j++)
                acc[i][j] = __builtin_amdgcn_mfma_f32_16x16x32_bf16(bf[j], af[i], acc[i][j], 0, 0, 0);
        __syncthreads();
    }

    float lsum = 0.f;
#pragma unroll
    for (int i = 0; i < 2; i++) {
        const size_t rowoff = (size_t)(m0 + wr + i * 16 + li) * NF;
#pragma unroll
        for (int j = 0; j < 4; j++) {
            int colb = n0 + wc + j * 16 + q * 4;
            float4 bd4 = *(const float4*)&bd[colb];
            float4 xr = *(const float4*)&X[rowoff + colb];
            float d0 = acc[i][j][0] + bd4.x - xr.x;
            float d1 = acc[i][j][1] + bd4.y - xr.y;
            float d2 = acc[i][j][2] + bd4.z - xr.z;
            float d3 = acc[i][j][3] + bd4.w - xr.w;
            lsum += d0 * d0 + d1 * d1 + d2 * d2 + d3 * d3;
        }
    }
#pragma unroll
    for (int o = 32; o; o >>= 1) lsum += __shfl_down(lsum, o);
    if (lane == 0) atomicAdd(mse_acc, lsum);
}

// ---------------------------------------------------------------------------
// compaction: cP = c[s==p], cR = c[s!=p] (order-free), wave-aggregated atomics
// ---------------------------------------------------------------------------
__global__ __launch_bounds__(256) void compact_kernel(
    const float* __restrict__ c, const int* __restrict__ s, const int* __restrict__ pv,
    float* __restrict__ cP, float* __restrict__ cR, int* __restrict__ cnt) {
    int i = blockIdx.x * 256 + threadIdx.x;
    float ci = c[i];
    bool pr = (s[i] == pv[0]);
    int lane = threadIdx.x & 63;
    unsigned long long m = __ballot(pr);
    {
        int cm = __popcll(m);
        int base = 0;
        if (lane == 0 && cm) base = atomicAdd(&cnt[0], cm);
        base = __shfl(base, 0);
        int off = __popcll(m & ((1ull << lane) - 1ull));
        if (pr) cP[base + off] = ci;
    }
    {
        unsigned long long mm = ~m;
        int cm = __popcll(mm);
        int base = 0;
        if (lane == 0 && cm) base = atomicAdd(&cnt[1], cm);
        base = __shfl(base, 0);
        int off = __popcll(mm & ((1ull << lane) - 1ull));
        if (!pr) cR[base + off] = ci;
    }
}

// ---------------------------------------------------------------------------
// pairwise masked L1: total += sum_{a in P, b in R} |cP[a]-cR[b]|
// 2 rows/thread, float4 LDS reads (broadcast), zero-pad + |ca| correction.
// ---------------------------------------------------------------------------
__global__ __launch_bounds__(256) void pair_kernel(
    const float* __restrict__ cP, const float* __restrict__ cR,
    const int* __restrict__ cnt, float* __restrict__ total) {
    __shared__ float sj[1024];
    const int nP = cnt[0], nR = cnt[1];
    const int jb = blockIdx.x * 1024;
    int jn = nR - jb; if (jn < 0) jn = 0; if (jn > 1024) jn = 1024;
    for (int j = threadIdx.x; j < 1024; j += 256)
        sj[j] = (jb + j < nR) ? cR[jb + j] : 0.f;
    __syncthreads();
    const int a0 = blockIdx.y * 512 + threadIdx.x;
    const int a1 = a0 + 256;
    const float ca0 = (a0 < nP) ? cP[a0] : 0.f;
    const float ca1 = (a1 < nP) ? cP[a1] : 0.f;
    float s0 = 0.f, s1 = 0.f;
#pragma unroll 4
    for (int j4 = 0; j4 < 256; j4++) {
        float4 v = *(const float4*)&sj[j4 * 4];
        s0 += fabsf(ca0 - v.x) + fabsf(ca0 - v.y) + fabsf(ca0 - v.z) + fabsf(ca0 - v.w);
        s1 += fabsf(ca1 - v.x) + fabsf(ca1 - v.y) + fabsf(ca1 - v.z) + fabsf(ca1 - v.w);
    }
    float pad = (float)(1024 - jn);
    s0 -= pad * fabsf(ca0);
    s1 -= pad * fabsf(ca1);
    if (a0 >= nP) s0 = 0.f;
    if (a1 >= nP) s1 = 0.f;
    float s = s0 + s1;
#pragma unroll
    for (int o = 32; o; o >>= 1) s += __shfl_down(s, o);
    if ((threadIdx.x & 63) == 0) atomicAdd(total, s);
}

// ---------------------------------------------------------------------------
__global__ void finalize_kernel(const float* __restrict__ accf, const int* __restrict__ acci,
                                float* __restrict__ out) {
    out[0] = accf[0] / (float)((size_t)NR * NF);  // mse mean
    out[1] = (float)NR;                           // rec.shape[0]
    int np = acci[2];
    out[2] = accf[1] / (float)np;                 // w_dist_mean
    out[3] = (float)np;                           // w_dist_count
}

extern "C" void kernel_launch(void* const* d_in, const int* in_sizes, int n_in,
                              void* d_out, int out_size, void* d_ws, size_t ws_size,
                              hipStream_t stream) {
    const float* X  = (const float*)d_in[0];
    const float* We = (const float*)d_in[1];
    const float* be = (const float*)d_in[2];
    const float* Wd = (const float*)d_in[3];
    const float* bd = (const float*)d_in[4];
    const float* Wc = (const float*)d_in[5];
    // bc (d_in[6]) is omitted: it cancels in |c_i - c_j|
    const int*   s  = (const int*)d_in[7];
    const int*   pv = (const int*)d_in[8];

    char* ws = (char*)d_ws;
    float* accf  = (float*)ws;                    // [0]=mse_sum, [1]=pair total
    int*   acci  = (int*)ws;                      // [2]=nP, [3]=nR
    float* cpart = (float*)(ws + 256);            // 16384 floats (bias-free critic scores)
    float* cP    = (float*)(ws + 256 + 65536);
    float* cR    = (float*)(ws + 256 + 2 * 65536);
    unsigned short* gbf = (unsigned short*)(ws + 256 + 3 * 65536);   // 8 MB
    unsigned short* WeT = gbf + (size_t)NR * NH;
    unsigned short* WdT = WeT + (size_t)NH * NF;

    (void)hipMemsetAsync(d_ws, 0, 256 + 65536, stream);
    prep_kernel<<<2048, 256, 0, stream>>>(We, Wd, WeT, WdT);
    gemm1_kernel<<<dim3(256, 2), 256, 0, stream>>>(X, WeT, be, Wc, gbf, cpart);
    gemm2_kernel<<<dim3(256, 8), 256, 0, stream>>>(gbf, WdT, bd, X, accf);
    compact_kernel<<<64, 256, 0, stream>>>(cpart, s, pv, cP, cR, acci + 2);
    pair_kernel<<<dim3(16, 32), 256, 0, stream>>>(cP, cR, acci + 2, accf + 1);
    finalize_kernel<<<1, 1, 0, stream>>>(accf, acci, (float*)d_out);
}

// Round 4
// 204.989 us; speedup vs baseline: 1.5067x; 1.5067x over previous
//
#include <hip/hip_runtime.h>
#include <hip/hip_bf16.h>
#include <cstdint>

// Problem constants (reference: N=16384, F=1024, H=256)
#define NR 16384
#define NF 1024
#define NH 256

typedef __bf16 bf16x8 __attribute__((ext_vector_type(8)));
typedef float f32x4 __attribute__((ext_vector_type(4)));
typedef unsigned short us8 __attribute__((ext_vector_type(8)));

static __device__ __forceinline__ unsigned short f2bf(float f) {
    unsigned u = __float_as_uint(f);
    u += 0x7FFFu + ((u >> 16) & 1u);   // RNE
    return (unsigned short)(u >> 16);
}
static __device__ __forceinline__ unsigned cvt2(float a, float b) {
    return ((unsigned)f2bf(b) << 16) | (unsigned)f2bf(a);
}

// async global->LDS, 16 B per lane; LDS dest must be wave-uniform base + lane*16
__device__ __forceinline__ void gl2lds16(const void* gp, void* lp) {
    __builtin_amdgcn_global_load_lds(
        (const __attribute__((address_space(1))) unsigned int*)gp,
        (__attribute__((address_space(3))) unsigned int*)lp, 16, 0, 0);
}

// ---------------------------------------------------------------------------
// LDS-tiled transpose+convert: dst_bf16[C][R] = src_f32[R][C]^T (coalesced both sides)
// grid (C/32, R/32), 256 threads
// ---------------------------------------------------------------------------
__global__ __launch_bounds__(256) void transpose_bf_kernel(
    const float* __restrict__ src, unsigned short* __restrict__ dst, int R, int C) {
    __shared__ float tile[32][33];
    const int c0 = blockIdx.x * 32, r0 = blockIdx.y * 32;
    const int t = threadIdx.x;
#pragma unroll
    for (int p = 0; p < 4; p++) {
        int idx = t + 256 * p;
        int r = idx >> 5, c = idx & 31;
        tile[r][c] = src[(size_t)(r0 + r) * C + c0 + c];
    }
    __syncthreads();
#pragma unroll
    for (int p = 0; p < 4; p++) {
        int idx = t + 256 * p;
        int rr = idx & 31, cc = idx >> 5;
        dst[(size_t)(c0 + cc) * R + r0 + rr] = f2bf(tile[rr][cc]);
    }
}

// ---------------------------------------------------------------------------
// GEMM1: g[16384][256](bf16) = X @ We + be ; cpart[row] = (g row).Wc  (no atomics)
// M-strip=32 (grid 512, ~2 blocks/CU), N=256 full, BK=32, double-buffered LDS,
// single-barrier pipelined loop: sync -> prefetch(next) -> compute(cur).
// ---------------------------------------------------------------------------
__global__ __launch_bounds__(256) void gemm1_kernel(
    const float* __restrict__ X, const unsigned short* __restrict__ WeT,
    const float* __restrict__ be, const float* __restrict__ Wc,
    unsigned short* __restrict__ g, float* __restrict__ cpart) {
    __shared__ float As[2][32 * 32];             // 4 KB each (fp32 X chunk)
    __shared__ unsigned short Bs[2][256 * 32];   // 16 KB each (bf16 WeT chunk)
    __shared__ float credu[4][32];
    const int t = threadIdx.x;
    const int m0 = blockIdx.x * 32;
    const int w = t >> 6, lane = t & 63, q = lane >> 4, li = lane & 15;
    const int nw = w * 64;   // wave n-slice

    // staging addresses (XOR k-chunk swizzle; measured conflict-free in R3)
    const int ar = t >> 3, acx = (t & 7) ^ (ar & 7);
    const float* Ag = X + (size_t)(m0 + ar) * NF + acx * 4;
    const int br = t >> 2, bcx = (t & 3) ^ ((br >> 1) & 3);
    const unsigned short* Bg = WeT + (size_t)br * NF + bcx * 8;

    f32x4 acc[2][4] = {};

    // prologue: stage k=0 into buffer 0
    gl2lds16(Ag, &As[0][t * 4]);
#pragma unroll
    for (int p = 0; p < 4; p++)
        gl2lds16(Bg + (size_t)(64 * p) * NF, &Bs[0][(t + 256 * p) * 8]);

    for (int it = 0; it < 32; ++it) {
        const int cur = it & 1;
        __syncthreads();                         // buffer[cur] ready
        if (it + 1 < 32) {                       // prefetch next into cur^1
            const int k1 = (it + 1) * 32;
            gl2lds16(Ag + k1, &As[cur ^ 1][t * 4]);
#pragma unroll
            for (int p = 0; p < 4; p++)
                gl2lds16(Bg + (size_t)(64 * p) * NF + k1, &Bs[cur ^ 1][(t + 256 * p) * 8]);
        }
        bf16x8 af[2], bfv[4];
#pragma unroll
        for (int i = 0; i < 2; i++) {
            int r = i * 16 + li;
            int s0 = (2 * q) ^ (r & 7);
            f32x4 lo = *(const f32x4*)&As[cur][r * 32 + s0 * 4];
            f32x4 hi = *(const f32x4*)&As[cur][r * 32 + (s0 ^ 1) * 4];
            uint4 pk;
            pk.x = cvt2(lo[0], lo[1]); pk.y = cvt2(lo[2], lo[3]);
            pk.z = cvt2(hi[0], hi[1]); pk.w = cvt2(hi[2], hi[3]);
            af[i] = __builtin_bit_cast(bf16x8, pk);
        }
#pragma unroll
        for (int j = 0; j < 4; j++) {
            int r = nw + j * 16 + li;
            int s = q ^ ((r >> 1) & 3);
            bfv[j] = __builtin_bit_cast(bf16x8, *(const us8*)&Bs[cur][r * 32 + s * 8]);
        }
#pragma unroll
        for (int i = 0; i < 2; i++)
#pragma unroll
            for (int j = 0; j < 4; j++)
                acc[i][j] = __builtin_amdgcn_mfma_f32_16x16x32_bf16(bfv[j], af[i], acc[i][j], 0, 0, 0);
    }

    // epilogue: g stores (ushort4) + critic partial dots; no atomics
#pragma unroll
    for (int i = 0; i < 2; i++) {
        float csum = 0.f;
#pragma unroll
        for (int j = 0; j < 4; j++) {
            int colb = nw + j * 16 + q * 4;
            float4 be4 = *(const float4*)&be[colb];
            float4 wc4 = *(const float4*)&Wc[colb];
            float v0 = acc[i][j][0] + be4.x;
            float v1 = acc[i][j][1] + be4.y;
            float v2 = acc[i][j][2] + be4.z;
            float v3 = acc[i][j][3] + be4.w;
            csum += v0 * wc4.x + v1 * wc4.y + v2 * wc4.z + v3 * wc4.w;
            ushort4 st = { f2bf(v0), f2bf(v1), f2bf(v2), f2bf(v3) };
            *(ushort4*)&g[(size_t)(m0 + i * 16 + li) * NH + colb] = st;
        }
        csum += __shfl_down(csum, 32);
        csum += __shfl_down(csum, 16);
        if (lane < 16) credu[w][i * 16 + lane] = csum;
    }
    __syncthreads();
    if (t < 32)
        cpart[m0 + t] = credu[0][t] + credu[1][t] + credu[2][t] + credu[3][t];
}

// ---------------------------------------------------------------------------
// GEMM2 fused MSE: rec = g @ Wd + bd; accumulate sum((rec-X)^2); rec never stored.
// M=64 x N=128, BK=32 (8 iters), dbuf 24 KB (~6 blocks/CU), pipelined loop.
// One atomic per block into a 64-cell partial array.
// ---------------------------------------------------------------------------
__global__ __launch_bounds__(256) void gemm2_kernel(
    const unsigned short* __restrict__ g, const unsigned short* __restrict__ WdT,
    const float* __restrict__ bd, const float* __restrict__ X,
    float* __restrict__ mseparts) {
    __shared__ unsigned short As[2][64 * 32];    // 4 KB each
    __shared__ unsigned short Bs[2][128 * 32];   // 8 KB each
    __shared__ float msred[4];
    const int t = threadIdx.x;
    const int m0 = blockIdx.x * 64;
    const int n0 = blockIdx.y * 128;
    const int w = t >> 6, lane = t & 63, q = lane >> 4, li = lane & 15;
    const int wr = (w >> 1) * 32, wn = (w & 1) * 64;

    const int r2 = t >> 2, c2 = (t & 3) ^ ((r2 >> 1) & 3);
    const unsigned short* Ag = g + (size_t)(m0 + r2) * NH + c2 * 8;
    const unsigned short* Bg = WdT + (size_t)(n0 + r2) * NH + c2 * 8;

    f32x4 acc[2][4] = {};

    gl2lds16(Ag, &As[0][t * 8]);
    gl2lds16(Bg, &Bs[0][t * 8]);
    gl2lds16(Bg + (size_t)64 * NH, &Bs[0][(t + 256) * 8]);

    for (int it = 0; it < 8; ++it) {
        const int cur = it & 1;
        __syncthreads();
        if (it + 1 < 8) {
            const int k1 = (it + 1) * 32;
            gl2lds16(Ag + k1, &As[cur ^ 1][t * 8]);
            gl2lds16(Bg + k1, &Bs[cur ^ 1][t * 8]);
            gl2lds16(Bg + (size_t)64 * NH + k1, &Bs[cur ^ 1][(t + 256) * 8]);
        }
        bf16x8 af[2], bfv[4];
#pragma unroll
        for (int i = 0; i < 2; i++) {
            int r = wr + i * 16 + li;
            int s = q ^ ((r >> 1) & 3);
            af[i] = __builtin_bit_cast(bf16x8, *(const us8*)&As[cur][r * 32 + s * 8]);
        }
#pragma unroll
        for (int j = 0; j < 4; j++) {
            int r = wn + j * 16 + li;
            int s = q ^ ((r >> 1) & 3);
            bfv[j] = __builtin_bit_cast(bf16x8, *(const us8*)&Bs[cur][r * 32 + s * 8]);
        }
#pragma unroll
        for (int i = 0; i < 2; i++)
#pragma unroll
            for (int j = 0; j < 4; j++)
                acc[i][j] = __builtin_amdgcn_mfma_f32_16x16x32_bf16(bfv[j], af[i], acc[i][j], 0, 0, 0);
    }

    float lsum = 0.f;
#pragma unroll
    for (int i = 0; i < 2; i++) {
        const size_t rowoff = (size_t)(m0 + wr + i * 16 + li) * NF;
#pragma unroll
        for (int j = 0; j < 4; j++) {
            int colb = n0 + wn + j * 16 + q * 4;
            float4 bd4 = *(const float4*)&bd[colb];
            float4 xr = *(const float4*)&X[rowoff + colb];
            float d0 = acc[i][j][0] + bd4.x - xr.x;
            float d1 = acc[i][j][1] + bd4.y - xr.y;
            float d2 = acc[i][j][2] + bd4.z - xr.z;
            float d3 = acc[i][j][3] + bd4.w - xr.w;
            lsum += d0 * d0 + d1 * d1 + d2 * d2 + d3 * d3;
        }
    }
#pragma unroll
    for (int o = 32; o; o >>= 1) lsum += __shfl_down(lsum, o);
    if (lane == 0) msred[w] = lsum;
    __syncthreads();
    if (t == 0)
        atomicAdd(&mseparts[(blockIdx.x * 8 + blockIdx.y) & 63],
                  msred[0] + msred[1] + msred[2] + msred[3]);
}

// ---------------------------------------------------------------------------
// compaction: cP = c[s==p], cR = c[s!=p] (order-free), wave-aggregated atomics
// ---------------------------------------------------------------------------
__global__ __launch_bounds__(256) void compact_kernel(
    const float* __restrict__ c, const int* __restrict__ s, const int* __restrict__ pv,
    float* __restrict__ cP, float* __restrict__ cR, int* __restrict__ cnt) {
    int i = blockIdx.x * 256 + threadIdx.x;
    float ci = c[i];
    bool pr = (s[i] == pv[0]);
    int lane = threadIdx.x & 63;
    unsigned long long m = __ballot(pr);
    {
        int cm = __popcll(m);
        int base = 0;
        if (lane == 0 && cm) base = atomicAdd(&cnt[0], cm);
        base = __shfl(base, 0);
        int off = __popcll(m & ((1ull << lane) - 1ull));
        if (pr) cP[base + off] = ci;
    }
    {
        unsigned long long mm = ~m;
        int cm = __popcll(mm);
        int base = 0;
        if (lane == 0 && cm) base = atomicAdd(&cnt[1], cm);
        base = __shfl(base, 0);
        int off = __popcll(mm & ((1ull << lane) - 1ull));
        if (!pr) cR[base + off] = ci;
    }
}

// ---------------------------------------------------------------------------
// pairwise masked L1: sum_{a in P, b in R} |cP[a]-cR[b]| -> 64 partial cells
// ---------------------------------------------------------------------------
__global__ __launch_bounds__(256) void pair_kernel(
    const float* __restrict__ cP, const float* __restrict__ cR,
    const int* __restrict__ cnt, float* __restrict__ pairparts) {
    __shared__ float sj[1024];
    const int nP = cnt[0], nR = cnt[1];
    const int jb = blockIdx.x * 1024;
    int jn = nR - jb; if (jn < 0) jn = 0; if (jn > 1024) jn = 1024;
    for (int j = threadIdx.x; j < 1024; j += 256)
        sj[j] = (jb + j < nR) ? cR[jb + j] : 0.f;
    __syncthreads();
    const int a0 = blockIdx.y * 512 + threadIdx.x;
    const int a1 = a0 + 256;
    const float ca0 = (a0 < nP) ? cP[a0] : 0.f;
    const float ca1 = (a1 < nP) ? cP[a1] : 0.f;
    float s0 = 0.f, s1 = 0.f;
#pragma unroll 4
    for (int j4 = 0; j4 < 256; j4++) {
        float4 v = *(const float4*)&sj[j4 * 4];
        s0 += fabsf(ca0 - v.x) + fabsf(ca0 - v.y) + fabsf(ca0 - v.z) + fabsf(ca0 - v.w);
        s1 += fabsf(ca1 - v.x) + fabsf(ca1 - v.y) + fabsf(ca1 - v.z) + fabsf(ca1 - v.w);
    }
    float pad = (float)(1024 - jn);
    s0 -= pad * fabsf(ca0);
    s1 -= pad * fabsf(ca1);
    if (a0 >= nP) s0 = 0.f;
    if (a1 >= nP) s1 = 0.f;
    float s = s0 + s1;
#pragma unroll
    for (int o = 32; o; o >>= 1) s += __shfl_down(s, o);
    if ((threadIdx.x & 63) == 0)
        atomicAdd(&pairparts[((blockIdx.y << 4) ^ blockIdx.x ^ (threadIdx.x >> 6)) & 63], s);
}

// ---------------------------------------------------------------------------
__global__ void finalize_kernel(const float* __restrict__ mseparts,
                                const float* __restrict__ pairparts,
                                const int* __restrict__ cnt, float* __restrict__ out) {
    float ms = 0.f, ps = 0.f;
    for (int i = 0; i < 64; i++) { ms += mseparts[i]; ps += pairparts[i]; }
    out[0] = ms / (float)((size_t)NR * NF);
    out[1] = (float)NR;
    out[2] = ps / (float)cnt[0];
    out[3] = (float)cnt[0];
}

extern "C" void kernel_launch(void* const* d_in, const int* in_sizes, int n_in,
                              void* d_out, int out_size, void* d_ws, size_t ws_size,
                              hipStream_t stream) {
    const float* X  = (const float*)d_in[0];
    const float* We = (const float*)d_in[1];
    const float* be = (const float*)d_in[2];
    const float* Wd = (const float*)d_in[3];
    const float* bd = (const float*)d_in[4];
    const float* Wc = (const float*)d_in[5];
    // bc (d_in[6]) omitted: cancels in |c_i - c_j|
    const int*   s  = (const int*)d_in[7];
    const int*   pv = (const int*)d_in[8];

    char* ws = (char*)d_ws;
    float* mseparts  = (float*)(ws + 0);        // 64 f
    float* pairparts = (float*)(ws + 256);      // 64 f
    int*   cnt       = (int*)(ws + 512);        // 2 ints
    float* cpart     = (float*)(ws + 1024);                 // 16384 f (plain stores)
    float* cP        = (float*)(ws + 1024 + 65536);
    float* cR        = (float*)(ws + 1024 + 2 * 65536);
    unsigned short* gbf = (unsigned short*)(ws + 1024 + 3 * 65536);  // 8 MB
    unsigned short* WeT = gbf + (size_t)NR * NH;            // [256][1024]
    unsigned short* WdT = WeT + (size_t)NH * NF;            // [1024][256]

    (void)hipMemsetAsync(d_ws, 0, 1024, stream);
    transpose_bf_kernel<<<dim3(8, 32), 256, 0, stream>>>(We, WeT, 1024, 256);
    transpose_bf_kernel<<<dim3(32, 8), 256, 0, stream>>>(Wd, WdT, 256, 1024);
    gemm1_kernel<<<512, 256, 0, stream>>>(X, WeT, be, Wc, gbf, cpart);
    gemm2_kernel<<<dim3(256, 8), 256, 0, stream>>>(gbf, WdT, bd, X, mseparts);
    compact_kernel<<<64, 256, 0, stream>>>(cpart, s, pv, cP, cR, cnt);
    pair_kernel<<<dim3(16, 32), 256, 0, stream>>>(cP, cR, cnt, pairparts);
    finalize_kernel<<<1, 1, 0, stream>>>(mseparts, pairparts, cnt, (float*)d_out);
}